// Round 11
// baseline (297.267 us; speedup 1.0000x reference)
//
#include <hip/hip_runtime.h>
#include <math.h>

typedef _Float16 half8  __attribute__((ext_vector_type(8)));
typedef _Float16 half4  __attribute__((ext_vector_type(4)));
typedef float    float4v __attribute__((ext_vector_type(4)));

#define NDIM   16
#define HID    128
#define NSTEP  10
#define RPW    2            // parents per WG; grid = 512 -> 2 WGs/CU
#define NROWS  48           // tile0: [x0,x1,xs0,xs1]x4 dup; tiles 1,2: tangents of p=0,1
#define XSTR   136          // hidden-activation row stride (halves)
#define XISTR  40           // layer-0 input row stride (halves)
#define SBS    17           // final-state row stride (fp32)

__device__ __forceinline__ float tanh_fast(float v) {
  float e = __expf(2.f * v);
  return 1.f - 2.f * __builtin_amdgcn_rcpf(e + 1.f);
}

// broadcast lane (4g+P) -> lanes 4g..4g+3 via DPP quad_perm (VALU pipe, no LDS)
template<int CTRL>
__device__ __forceinline__ float qbcast(float v) {
  int i = __builtin_amdgcn_update_dpp(0, __builtin_bit_cast(int, v), CTRL, 0xF, 0xF, true);
  return __builtin_bit_cast(float, i);
}

// r9's PROVEN permuted neuron storage: storage col c = 32*v + 8*q + 4*mt + r
// (v = virtual r9-wave 0..3) holds original neuron:
__device__ __forceinline__ int oneuron(int c) {
  return 32*(c >> 5) + 16*((c >> 2) & 1) + 4*((c >> 3) & 3) + (c & 3);
}

// W=2 via mechanical v-loop wrap of the passing r9 kernel: 2 physical waves,
// wave mi executes r9-waves v = 2mi+h (h=0,1) in an inner loop. All LDS
// layouts, oneuron, finish writes, RK and solve code are byte-identical to r9.
// v=3 participates in the GEMM (M-tiles 6,7 / storage cols 96..127) but owns
// no N-tile (r9's mi<3 gate becomes v<3). B-fragments are loaded ONCE per ks
// and reused across both v's M-tiles -> per-CU LDS reads halve vs r9.
// Registers ~390 -> 1 wave/SIMD (launch_bounds(128,1); no spill through 450).
__global__ __launch_bounds__(128, 1)
void flow_ode_kernel(const float* __restrict__ gx,  const float* __restrict__ gxs,
                     const float* __restrict__ W0,  const float* __restrict__ b0,
                     const float* __restrict__ W1,  const float* __restrict__ b1,
                     const float* __restrict__ W2,  const float* __restrict__ b2,
                     const float* __restrict__ W3,  const float* __restrict__ b3,
                     const float* __restrict__ W4,  const float* __restrict__ b4,
                     float* __restrict__ out)
{
  __shared__ __align__(16) _Float16 XT[2][NROWS][XSTR];  // hidden activations ping-pong
  __shared__ __align__(16) _Float16 XI[NROWS][XISTR];    // layer-0 input
  __shared__ float SbL[NROWS][SBS];                      // final state (solve only)

  const int tid  = threadIdx.x;
  const int mi   = tid >> 6;       // 0 or 1
  const int lane = tid & 63;
  const int q    = lane >> 4;
  const int ln   = lane & 15;
  const int g0   = blockIdx.x * RPW;

  // ---------------- weight fragments (r9 permuted storage order) ----------------
  half8 A0[2][2];                       // [h][mt]
  half8 A1[2][2][4], A2[2][2][4], A3[2][2][4];
  half8 A4[4];
  float bw[4][2][2][4];                 // [layer][h][mt][r]
  float b4r[4];

  #pragma unroll
  for (int h = 0; h < 2; ++h) {
    const int v = 2*mi + h;
    #pragma unroll
    for (int mt = 0; mt < 2; ++mt) {
      const int m = 16*(2*v + mt) + ln;      // original out-neuron for A-row ln
      #pragma unroll
      for (int j = 0; j < 8; ++j) {
        const int k = 8*q + j;               // XI cols are unpermuted
        A0[h][mt][j] = (k < NDIM+1) ? (_Float16)W0[k*HID + m] : (_Float16)0.f;
      }
      #pragma unroll
      for (int ks = 0; ks < 4; ++ks) {
        #pragma unroll
        for (int j = 0; j < 8; ++j) {
          const int k = oneuron(32*ks + 8*q + j);   // storage col -> original neuron
          A1[h][mt][ks][j] = (_Float16)W1[k*HID + m];
          A2[h][mt][ks][j] = (_Float16)W2[k*HID + m];
          A3[h][mt][ks][j] = (_Float16)W3[k*HID + m];
        }
      }
      #pragma unroll
      for (int r = 0; r < 4; ++r) {
        const int mm = 16*(2*v + mt) + 4*q + r;
        bw[0][h][mt][r] = b0[mm];
        bw[1][h][mt][r] = b1[mm];
        bw[2][h][mt][r] = b2[mm];
        bw[3][h][mt][r] = b3[mm];
      }
    }
  }
  #pragma unroll
  for (int ks = 0; ks < 4; ++ks)
    #pragma unroll
    for (int j = 0; j < 8; ++j)
      A4[ks][j] = (_Float16)W4[oneuron(32*ks + 8*q + j)*NDIM + ln];
  #pragma unroll
  for (int r = 0; r < 4; ++r) b4r[r] = b4[4*q + r];

  // ---------------- RK state in registers ----------------
  // slot h holds the state of owned N-tile v=2mi+h (valid when v<3):
  // wave0: tile0 (primal, slot0) + tile1 (p0 tangents, slot1); wave1: tile2 (p1 tangents, slot0)
  float sbr[2][4], sar[2][4];
  if (mi == 0) {
    const int p = ln & 3;                                // [x0,x1,xs0,xs1] pattern
    const float* src = (p < 2) ? (gx + (g0 + p)*NDIM) : (gxs + (g0 + p - 2)*NDIM);
    #pragma unroll
    for (int r = 0; r < 4; ++r) {
      sbr[0][r] = src[4*q + r];
      sbr[1][r] = (ln == 4*q + r) ? 1.f : 0.f;
    }
  } else {
    #pragma unroll
    for (int r = 0; r < 4; ++r) {
      sbr[0][r] = (ln == 4*q + r) ? 1.f : 0.f;
      sbr[1][r] = 0.f;
    }
  }
  #pragma unroll
  for (int h = 0; h < 2; ++h)
    #pragma unroll
    for (int r = 0; r < 4; ++r) sar[h][r] = 0.f;

  // ---------------- init XI (cols 0..31; 16..31 zeroed once, t(=0) included) ----------------
  for (int idx = tid; idx < NROWS*32; idx += 128)
    XI[idx >> 5][idx & 31] = (_Float16)0.f;
  __syncthreads();
  #pragma unroll
  for (int h = 0; h < 2; ++h) {
    const int v = 2*mi + h;
    if (v < 3) {
      half4 x4;
      #pragma unroll
      for (int r = 0; r < 4; ++r) x4[r] = (_Float16)sbr[h][r];
      *(half4*)&XI[v*16 + ln][4*q] = x4;
    }
  }
  __syncthreads();

  // phase-offset odd WGs ~half a layer period (r9 win)
  if (blockIdx.x & 1) __builtin_amdgcn_s_sleep(22);

  const float dt = 1.f / NSTEP;

  // epilogue: per v exactly r9's finish — tile0 tanh, tiles 1,2 scaled by
  // quad_perm-broadcast (1-h^2) of the parent; 3 b128 writes per v.
  auto finish = [&](float4v (&D)[2][2][3], int wb) {
    #pragma unroll
    for (int h = 0; h < 2; ++h) {
      const int v = 2*mi + h;
      float ss[2][4];
      half8 hh;
      #pragma unroll
      for (int mt = 0; mt < 2; ++mt)
        #pragma unroll
        for (int r = 0; r < 4; ++r) {
          const float hv = tanh_fast(D[h][mt][0][r]);
          hh[4*mt + r] = (_Float16)hv;
          ss[mt][r] = 1.f - hv*hv;
        }
      *(half8*)&XT[wb][ln][32*v + 8*q] = hh;
      half8 t1, t2;
      #pragma unroll
      for (int mt = 0; mt < 2; ++mt)
        #pragma unroll
        for (int r = 0; r < 4; ++r) {
          t1[4*mt + r] = (_Float16)(D[h][mt][1][r] * qbcast<0x00>(ss[mt][r]));   // parent 0
          t2[4*mt + r] = (_Float16)(D[h][mt][2][r] * qbcast<0x55>(ss[mt][r]));   // parent 1
        }
      *(half8*)&XT[wb][16 + ln][32*v + 8*q] = t1;
      *(half8*)&XT[wb][32 + ln][32*v + 8*q] = t2;
    }
    __syncthreads();
  };

  auto mid_layer = [&](const half8 (&A)[2][2][4], const float (&bb)[2][2][4], int rb, int wb) {
    float4v D[2][2][3];
    #pragma unroll
    for (int h = 0; h < 2; ++h)
      #pragma unroll
      for (int mt = 0; mt < 2; ++mt)
        #pragma unroll
        for (int nt = 0; nt < 3; ++nt)
          #pragma unroll
          for (int e = 0; e < 4; ++e) D[h][mt][nt][e] = (nt == 0) ? bb[h][mt][e] : 0.f;
    #pragma unroll
    for (int ks = 0; ks < 4; ++ks) {
      half8 Bf[3];
      #pragma unroll
      for (int nt = 0; nt < 3; ++nt)
        Bf[nt] = *(const half8*)&XT[rb][nt*16 + ln][32*ks + 8*q];
      #pragma unroll
      for (int h = 0; h < 2; ++h)
        #pragma unroll
        for (int mt = 0; mt < 2; ++mt)
          #pragma unroll
          for (int nt = 0; nt < 3; ++nt)
            D[h][mt][nt] = __builtin_amdgcn_mfma_f32_16x16x32_f16(A[h][mt][ks], Bf[nt], D[h][mt][nt], 0, 0, 0);
    }
    finish(D, wb);
  };

  // ---------------- 10 RK4 steps x 4 stages ----------------
  #pragma unroll 1
  for (int step = 0; step < NSTEP; ++step) {
    const float t0 = step * dt;
    #pragma unroll
    for (int stage = 0; stage < 4; ++stage) {
      { // ---- layer 0 (K = 32 from XI) -> XT[0] ----
        float4v D[2][2][3];
        #pragma unroll
        for (int h = 0; h < 2; ++h)
          #pragma unroll
          for (int mt = 0; mt < 2; ++mt)
            #pragma unroll
            for (int nt = 0; nt < 3; ++nt)
              #pragma unroll
              for (int e = 0; e < 4; ++e) D[h][mt][nt][e] = (nt == 0) ? bw[0][h][mt][e] : 0.f;
        half8 Bf[3];
        #pragma unroll
        for (int nt = 0; nt < 3; ++nt)
          Bf[nt] = *(const half8*)&XI[nt*16 + ln][8*q];
        #pragma unroll
        for (int h = 0; h < 2; ++h)
          #pragma unroll
          for (int mt = 0; mt < 2; ++mt)
            #pragma unroll
            for (int nt = 0; nt < 3; ++nt)
              D[h][mt][nt] = __builtin_amdgcn_mfma_f32_16x16x32_f16(A0[h][mt], Bf[nt], D[h][mt][nt], 0, 0, 0);
        finish(D, 0);
      }
      mid_layer(A1, bw[1], 0, 1);
      mid_layer(A2, bw[2], 1, 0);
      mid_layer(A3, bw[3], 0, 1);
      { // ---- layer 4 (reads XT[1]) + RK update: v<3 owns tile v, slot h ----
        #pragma unroll
        for (int h = 0; h < 2; ++h) {
          const int v = 2*mi + h;
          if (v < 3) {
            float4v Da;
            #pragma unroll
            for (int e = 0; e < 4; ++e) Da[e] = (v == 0) ? b4r[e] : 0.f;
            #pragma unroll
            for (int ks = 0; ks < 4; ++ks) {
              half8 Ba = *(const half8*)&XT[1][v*16 + ln][32*ks + 8*q];
              Da = __builtin_amdgcn_mfma_f32_16x16x32_f16(A4[ks], Ba, Da, 0, 0, 0);
            }
            const float c_s = (stage < 2) ? 0.5f*dt : dt;
            half4 xn;
            if (stage < 3) {
              const float w_s = (stage == 0) ? 1.f : 2.f;
              #pragma unroll
              for (int r = 0; r < 4; ++r) {
                sar[h][r] += w_s * Da[r];
                xn[r] = (_Float16)(sbr[h][r] + c_s * Da[r]);
              }
            } else {
              #pragma unroll
              for (int r = 0; r < 4; ++r) {
                const float nb = sbr[h][r] + (dt * (1.f/6.f)) * (sar[h][r] + Da[r]);
                sbr[h][r] = nb;
                sar[h][r] = 0.f;
                xn[r] = (_Float16)nb;
              }
            }
            *(half4*)&XI[v*16 + ln][4*q] = xn;
            if (v == 0 && q == 0)
              XI[ln][16] = (_Float16)(t0 + c_s);       // t column (primal rows)
          }
        }
        __syncthreads();
      }
    }
  }

  // ---------------- dump state, then per-parent solve ----------------
  #pragma unroll
  for (int h = 0; h < 2; ++h) {
    const int v = 2*mi + h;
    if (v < 3) {
      #pragma unroll
      for (int r = 0; r < 4; ++r)
        SbL[v*16 + ln][4*q + r] = sbr[h][r];
    }
  }
  __syncthreads();

  { // wave mi solves parent mi
    const int p    = mi;
    const int jj   = ln;
    const int base = lane & 48;
    float c[NDIM], gv[NDIM], G[NDIM];
    #pragma unroll
    for (int i = 0; i < NDIM; ++i) c[i] = SbL[16 + 16*p + jj][i];   // J[:, jj]
    float n2 = 0.f;
    #pragma unroll
    for (int i = 0; i < NDIM; ++i) {
      gv[i] = SbL[p][i] - SbL[2 + p][i];                            // y - y*
      n2 += gv[i]*gv[i];
    }
    const float rinv = 1.f / (sqrtf(n2) + 1e-8f);
    float rhs = 0.f;
    #pragma unroll
    for (int i = 0; i < NDIM; ++i) rhs += c[i] * gv[i];
    rhs *= rinv;
    #pragma unroll
    for (int k = 0; k < NDIM; ++k) {
      float acc = (k == jj) ? 1e-6f : 0.f;
      #pragma unroll
      for (int i = 0; i < NDIM; ++i)
        acc += c[i] * __shfl(c[i], base + k, 64);
      G[k] = acc;
    }
    #pragma unroll
    for (int k = 0; k < NDIM-1; ++k) {
      const float piv  = __shfl(G[k], base + k, 64);
      const float prhs = __shfl(rhs,  base + k, 64);
      const float f = (jj > k) ? G[k] / piv : 0.f;
      #pragma unroll
      for (int cc = k; cc < NDIM; ++cc)
        G[cc] -= f * __shfl(G[cc], base + k, 64);
      rhs -= f * prhs;
    }
    float sol = 0.f;
    #pragma unroll
    for (int k = NDIM-1; k >= 0; --k) {
      const float piv = __shfl(G[k], base + k, 64);
      const float pr  = __shfl(rhs,  base + k, 64);
      const float xk  = pr / piv;
      if (jj == k) sol = xk;
      if (jj <  k) rhs -= G[k] * xk;
    }
    if (lane < NDIM)
      out[(g0 + p)*NDIM + jj] = -sol;
  }
}

extern "C" void kernel_launch(void* const* d_in, const int* in_sizes, int n_in,
                              void* d_out, int out_size, void* d_ws, size_t ws_size,
                              hipStream_t stream) {
  (void)in_sizes; (void)n_in; (void)d_ws; (void)ws_size; (void)out_size;
  flow_ode_kernel<<<dim3(512), dim3(128), 0, stream>>>(
      (const float*)d_in[0],  (const float*)d_in[1],
      (const float*)d_in[2],  (const float*)d_in[3],
      (const float*)d_in[4],  (const float*)d_in[5],
      (const float*)d_in[6],  (const float*)d_in[7],
      (const float*)d_in[8],  (const float*)d_in[9],
      (const float*)d_in[10], (const float*)d_in[11],
      (float*)d_out);
}

// Round 12
// 237.563 us; speedup vs baseline: 1.2513x; 1.2513x over previous
//
#include <hip/hip_runtime.h>
#include <math.h>

typedef _Float16 half8  __attribute__((ext_vector_type(8)));
typedef _Float16 half4  __attribute__((ext_vector_type(4)));
typedef float    float4v __attribute__((ext_vector_type(4)));

#define NDIM   16
#define HID    128
#define NSTEP  10
#define RPW    2            // parents per WG; grid = 512 -> 2 WGs/CU
#define NROWS  48           // tile0: [x0,x1,xs0,xs1]x4 dup; tiles 1,2: tangents of p=0,1
#define XSTR   136          // hidden-activation row stride (halves)
#define XISTR  40           // layer-0 input row stride (halves)
#define SBS    17           // final-state row stride (fp32)

__device__ __forceinline__ float tanh_fast(float v) {
  // 1 - 2/(e^{2v}+1); rcp via v_rcp_f32 (1 trans inst, ~1e-6 rel err, far
  // below f16 storage granularity) instead of the ~10-inst exact div sequence.
  float e = __expf(2.f * v);
  return 1.f - 2.f * __builtin_amdgcn_rcpf(e + 1.f);
}

// broadcast lane (4g+P) -> lanes 4g..4g+3 via DPP quad_perm (VALU pipe, no LDS)
template<int CTRL>
__device__ __forceinline__ float qbcast(float v) {
  int i = __builtin_amdgcn_update_dpp(0, __builtin_bit_cast(int, v), CTRL, 0xF, 0xF, true);
  return __builtin_bit_cast(float, i);
}

// Permuted neuron storage: each lane's epilogue outputs (2 M-tiles x 4 C-rows)
// are 8 contiguous halves -> one ds_write_b128. Storage col c holds original
// neuron oneuron(c); weights are loaded with the inverse permutation.
__device__ __forceinline__ int oneuron(int c) {
  return 32*(c >> 5) + 16*((c >> 2) & 1) + 4*((c >> 3) & 3) + (c & 3);
}

// STRUCTURE (measured optimum of the family, r1-r11 sweep):
// 4 waves/WG, wave mi owns original neurons 32mi..32mi+31 (2 M-tiles), all 3
// N-tiles. tile0 = [x0,x1,xs0,xs1]x4 (quad_perm tanh' broadcast); tiles 1,2 =
// tangents. RK state in registers of the tile-owning wave. 2 WGs/CU,
// phase-offset so the two barrier domains interleave LDS-port bursts.
// - W=8 (r6) and W=2 (r11) both slower: traffic prop. to waves covering M,
//   register pressure prop. to M-width/wave; r9 is the saddle.
// - weight set ~170 regs -> 2 waves/SIMD hard cap; tighter bounds spill (r8).
__global__ __launch_bounds__(256, 2)
void flow_ode_kernel(const float* __restrict__ gx,  const float* __restrict__ gxs,
                     const float* __restrict__ W0,  const float* __restrict__ b0,
                     const float* __restrict__ W1,  const float* __restrict__ b1,
                     const float* __restrict__ W2,  const float* __restrict__ b2,
                     const float* __restrict__ W3,  const float* __restrict__ b3,
                     const float* __restrict__ W4,  const float* __restrict__ b4,
                     float* __restrict__ out)
{
  __shared__ __align__(16) _Float16 XT[2][NROWS][XSTR];  // hidden activations ping-pong
  __shared__ __align__(16) _Float16 XI[NROWS][XISTR];    // layer-0 input
  __shared__ float SbL[NROWS][SBS];                      // final state (solve only)

  const int tid  = threadIdx.x;
  const int mi   = tid >> 6;
  const int lane = tid & 63;
  const int q    = lane >> 4;
  const int ln   = lane & 15;
  const int g0   = blockIdx.x * RPW;

  // ---------------- weight fragments (permuted storage order) ----------------
  half8 A0[2];
  half8 A1[2][4], A2[2][4], A3[2][4];
  half8 A4[4];
  float bw[4][2][4];
  float b4r[4];

  #pragma unroll
  for (int mt = 0; mt < 2; ++mt) {
    const int m = 16*(2*mi + mt) + ln;       // original out-neuron for A-row ln
    #pragma unroll
    for (int j = 0; j < 8; ++j) {
      const int k = 8*q + j;                 // XI cols are unpermuted
      A0[mt][j] = (k < NDIM+1) ? (_Float16)W0[k*HID + m] : (_Float16)0.f;
    }
    #pragma unroll
    for (int ks = 0; ks < 4; ++ks) {
      #pragma unroll
      for (int j = 0; j < 8; ++j) {
        const int k = oneuron(32*ks + 8*q + j);   // storage col -> original neuron
        A1[mt][ks][j] = (_Float16)W1[k*HID + m];
        A2[mt][ks][j] = (_Float16)W2[k*HID + m];
        A3[mt][ks][j] = (_Float16)W3[k*HID + m];
      }
    }
  }
  #pragma unroll
  for (int ks = 0; ks < 4; ++ks)
    #pragma unroll
    for (int j = 0; j < 8; ++j)
      A4[ks][j] = (_Float16)W4[oneuron(32*ks + 8*q + j)*NDIM + ln];

  #pragma unroll
  for (int mt = 0; mt < 2; ++mt)
    #pragma unroll
    for (int r = 0; r < 4; ++r) {
      const int m = 16*(2*mi + mt) + 4*q + r;
      bw[0][mt][r] = b0[m];
      bw[1][mt][r] = b1[m];
      bw[2][mt][r] = b2[m];
      bw[3][mt][r] = b3[m];
    }
  #pragma unroll
  for (int r = 0; r < 4; ++r) b4r[r] = b4[4*q + r];

  // ---------------- RK state in registers ----------------
  // wave mi (<3) owns tile mi; lane (q,ln): row ln, dims 4q+r.
  float sbr[4], sar[4];
  if (mi == 0) {
    const int p = ln & 3;                                // [x0,x1,xs0,xs1] pattern
    const float* src = (p < 2) ? (gx + (g0 + p)*NDIM) : (gxs + (g0 + p - 2)*NDIM);
    #pragma unroll
    for (int r = 0; r < 4; ++r) sbr[r] = src[4*q + r];
  } else {
    #pragma unroll
    for (int r = 0; r < 4; ++r) sbr[r] = (ln == 4*q + r) ? 1.f : 0.f;  // tangent e_ln
  }
  #pragma unroll
  for (int r = 0; r < 4; ++r) sar[r] = 0.f;

  // ---------------- init XI (cols 0..31; 16..31 zeroed once, t(=0) included) ----------------
  for (int idx = tid; idx < NROWS*32; idx += 256)
    XI[idx >> 5][idx & 31] = (_Float16)0.f;
  __syncthreads();
  if (mi < 3) {
    half4 x4;
    #pragma unroll
    for (int r = 0; r < 4; ++r) x4[r] = (_Float16)sbr[r];
    *(half4*)&XI[mi*16 + ln][4*q] = x4;
  }
  __syncthreads();

  // phase-offset odd WGs by ~half a layer period (~1400 cyc) so the two
  // co-resident barrier domains interleave LDS-port bursts instead of
  // phase-locking. Uniform branch; no correctness impact.
  if (blockIdx.x & 1) __builtin_amdgcn_s_sleep(22);

  const float dt = 1.f / NSTEP;

  // epilogue: tile0 -> tanh (bias pre-folded in C-init); tiles 1,2 -> scale by
  // quad_perm-broadcast (1-h^2) of the parent. One b128 write per N-tile.
  auto finish = [&](float4v (&D)[2][3], int wb) {
    float ss[2][4];
    half8 hh;
    #pragma unroll
    for (int mt = 0; mt < 2; ++mt)
      #pragma unroll
      for (int r = 0; r < 4; ++r) {
        const float h = tanh_fast(D[mt][0][r]);
        hh[4*mt + r] = (_Float16)h;
        ss[mt][r] = 1.f - h*h;
      }
    *(half8*)&XT[wb][ln][32*mi + 8*q] = hh;
    half8 t1, t2;
    #pragma unroll
    for (int mt = 0; mt < 2; ++mt)
      #pragma unroll
      for (int r = 0; r < 4; ++r) {
        t1[4*mt + r] = (_Float16)(D[mt][1][r] * qbcast<0x00>(ss[mt][r]));   // parent 0
        t2[4*mt + r] = (_Float16)(D[mt][2][r] * qbcast<0x55>(ss[mt][r]));   // parent 1
      }
    *(half8*)&XT[wb][16 + ln][32*mi + 8*q] = t1;
    *(half8*)&XT[wb][32 + ln][32*mi + 8*q] = t2;
    __syncthreads();
  };

  auto mid_layer = [&](const half8 (&A)[2][4], const float (&bb)[2][4], int rb, int wb) {
    float4v D[2][3];
    #pragma unroll
    for (int mt = 0; mt < 2; ++mt)
      #pragma unroll
      for (int nt = 0; nt < 3; ++nt)
        #pragma unroll
        for (int e = 0; e < 4; ++e) D[mt][nt][e] = (nt == 0) ? bb[mt][e] : 0.f;
    #pragma unroll
    for (int ks = 0; ks < 4; ++ks) {
      half8 Bf[3];
      #pragma unroll
      for (int nt = 0; nt < 3; ++nt)
        Bf[nt] = *(const half8*)&XT[rb][nt*16 + ln][32*ks + 8*q];
      #pragma unroll
      for (int nt = 0; nt < 3; ++nt) {
        D[0][nt] = __builtin_amdgcn_mfma_f32_16x16x32_f16(A[0][ks], Bf[nt], D[0][nt], 0, 0, 0);
        D[1][nt] = __builtin_amdgcn_mfma_f32_16x16x32_f16(A[1][ks], Bf[nt], D[1][nt], 0, 0, 0);
      }
    }
    finish(D, wb);
  };

  // ---------------- 10 RK4 steps x 4 stages (stage loop fully unrolled) ----------------
  #pragma unroll 1
  for (int step = 0; step < NSTEP; ++step) {
    const float t0 = step * dt;
    #pragma unroll
    for (int stage = 0; stage < 4; ++stage) {
      { // ---- layer 0 (K = 32 from XI) -> XT[0] ----
        float4v D[2][3];
        #pragma unroll
        for (int mt = 0; mt < 2; ++mt)
          #pragma unroll
          for (int nt = 0; nt < 3; ++nt)
            #pragma unroll
            for (int e = 0; e < 4; ++e) D[mt][nt][e] = (nt == 0) ? bw[0][mt][e] : 0.f;
        half8 Bf[3];
        #pragma unroll
        for (int nt = 0; nt < 3; ++nt)
          Bf[nt] = *(const half8*)&XI[nt*16 + ln][8*q];
        #pragma unroll
        for (int nt = 0; nt < 3; ++nt) {
          D[0][nt] = __builtin_amdgcn_mfma_f32_16x16x32_f16(A0[0], Bf[nt], D[0][nt], 0, 0, 0);
          D[1][nt] = __builtin_amdgcn_mfma_f32_16x16x32_f16(A0[1], Bf[nt], D[1][nt], 0, 0, 0);
        }
        finish(D, 0);
      }
      mid_layer(A1, bw[1], 0, 1);
      mid_layer(A2, bw[2], 1, 0);
      mid_layer(A3, bw[3], 0, 1);
      { // ---- layer 4 (reads XT[1]) + RK update: waves 0..2 own tiles 0..2 ----
        if (mi < 3) {
          float4v Da;
          #pragma unroll
          for (int e = 0; e < 4; ++e) Da[e] = (mi == 0) ? b4r[e] : 0.f;
          #pragma unroll
          for (int ks = 0; ks < 4; ++ks) {
            half8 Ba = *(const half8*)&XT[1][mi*16 + ln][32*ks + 8*q];
            Da = __builtin_amdgcn_mfma_f32_16x16x32_f16(A4[ks], Ba, Da, 0, 0, 0);
          }
          const float c_s = (stage < 2) ? 0.5f*dt : dt;
          half4 xn;
          if (stage < 3) {
            const float w_s = (stage == 0) ? 1.f : 2.f;
            #pragma unroll
            for (int r = 0; r < 4; ++r) {
              sar[r] += w_s * Da[r];
              xn[r] = (_Float16)(sbr[r] + c_s * Da[r]);
            }
          } else {
            #pragma unroll
            for (int r = 0; r < 4; ++r) {
              const float nb = sbr[r] + (dt * (1.f/6.f)) * (sar[r] + Da[r]);
              sbr[r] = nb;
              sar[r] = 0.f;
              xn[r] = (_Float16)nb;
            }
          }
          *(half4*)&XI[mi*16 + ln][4*q] = xn;
          if (mi == 0 && q == 0)
            XI[ln][16] = (_Float16)(t0 + ((stage < 2) ? 0.5f*dt : dt));  // t column
        }
        __syncthreads();
      }
    }
  }

  // ---------------- dump state, then per-parent solve ----------------
  if (mi < 3) {
    #pragma unroll
    for (int r = 0; r < 4; ++r)
      SbL[mi*16 + ln][4*q + r] = sbr[r];
  }
  __syncthreads();

  if (mi < RPW) {
    const int p    = mi;
    const int jj   = ln;
    const int base = lane & 48;
    float c[NDIM], gv[NDIM], G[NDIM];
    #pragma unroll
    for (int i = 0; i < NDIM; ++i) c[i] = SbL[16 + 16*p + jj][i];   // J[:, jj]
    float n2 = 0.f;
    #pragma unroll
    for (int i = 0; i < NDIM; ++i) {
      // tile0 col layout [x0,x1,xs0,xs1]x4: x_p at col p, xs_p at col 2+p
      gv[i] = SbL[p][i] - SbL[2 + p][i];                            // y - y*
      n2 += gv[i]*gv[i];
    }
    const float rinv = 1.f / (sqrtf(n2) + 1e-8f);
    float rhs = 0.f;
    #pragma unroll
    for (int i = 0; i < NDIM; ++i) rhs += c[i] * gv[i];
    rhs *= rinv;
    #pragma unroll
    for (int k = 0; k < NDIM; ++k) {
      float acc = (k == jj) ? 1e-6f : 0.f;
      #pragma unroll
      for (int i = 0; i < NDIM; ++i)
        acc += c[i] * __shfl(c[i], base + k, 64);
      G[k] = acc;
    }
    #pragma unroll
    for (int k = 0; k < NDIM-1; ++k) {
      const float piv  = __shfl(G[k], base + k, 64);
      const float prhs = __shfl(rhs,  base + k, 64);
      const float f = (jj > k) ? G[k] / piv : 0.f;
      #pragma unroll
      for (int cc = k; cc < NDIM; ++cc)
        G[cc] -= f * __shfl(G[cc], base + k, 64);
      rhs -= f * prhs;
    }
    float sol = 0.f;
    #pragma unroll
    for (int k = NDIM-1; k >= 0; --k) {
      const float piv = __shfl(G[k], base + k, 64);
      const float pr  = __shfl(rhs,  base + k, 64);
      const float xk  = pr / piv;
      if (jj == k) sol = xk;
      if (jj <  k) rhs -= G[k] * xk;
    }
    if (lane < NDIM)
      out[(g0 + p)*NDIM + jj] = -sol;
  }
}

extern "C" void kernel_launch(void* const* d_in, const int* in_sizes, int n_in,
                              void* d_out, int out_size, void* d_ws, size_t ws_size,
                              hipStream_t stream) {
  (void)in_sizes; (void)n_in; (void)d_ws; (void)ws_size; (void)out_size;
  flow_ode_kernel<<<dim3(512), dim3(256), 0, stream>>>(
      (const float*)d_in[0],  (const float*)d_in[1],
      (const float*)d_in[2],  (const float*)d_in[3],
      (const float*)d_in[4],  (const float*)d_in[5],
      (const float*)d_in[6],  (const float*)d_in[7],
      (const float*)d_in[8],  (const float*)d_in[9],
      (const float*)d_in[10], (const float*)d_in[11],
      (float*)d_out);
}